// Round 1
// baseline (1003.262 us; speedup 1.0000x reference)
//
#include <hip/hip_runtime.h>
#include <hip/hip_bf16.h>
#include <math.h>

// Problem constants
#define BQ   16384        // windows
#define SEQN 4            // tokens per window
#define CH   512
#define NH   8
#define HDIM 64
#define HID  2048
#define NTOK (BQ*SEQN)    // 65536 rows

using bf16 = __hip_bfloat16;
typedef __bf16 bf16x8 __attribute__((ext_vector_type(8)));
typedef float  f32x4  __attribute__((ext_vector_type(4)));

// ---------------- fp32 -> bf16 convert ----------------
__global__ __launch_bounds__(256) void f2b_kernel(const float* __restrict__ in,
                                                  bf16* __restrict__ out, int n) {
    int i = (blockIdx.x * 256 + threadIdx.x) * 4;
    if (i + 3 < n) {
        float4 v = *(const float4*)&in[i];
        __align__(8) bf16 t[4];
        t[0] = __float2bfloat16(v.x);
        t[1] = __float2bfloat16(v.y);
        t[2] = __float2bfloat16(v.z);
        t[3] = __float2bfloat16(v.w);
        *(uint2*)&out[i] = *(const uint2*)t;
    }
}

// ---------------- LayerNorm (fp32 in, bf16 out), one wave per row ----------------
__global__ __launch_bounds__(256) void ln_kernel(const float* __restrict__ x,
                                                 const float* __restrict__ g,
                                                 const float* __restrict__ b,
                                                 bf16* __restrict__ out) {
    int row  = blockIdx.x * 4 + (threadIdx.x >> 6);
    int lane = threadIdx.x & 63;
    const float* xr = x + (size_t)row * CH;
    int c0 = lane * 8;
    float4 v0 = *(const float4*)&xr[c0];
    float4 v1 = *(const float4*)&xr[c0 + 4];
    float s  = v0.x + v0.y + v0.z + v0.w + v1.x + v1.y + v1.z + v1.w;
    float sq = v0.x*v0.x + v0.y*v0.y + v0.z*v0.z + v0.w*v0.w
             + v1.x*v1.x + v1.y*v1.y + v1.z*v1.z + v1.w*v1.w;
#pragma unroll
    for (int off = 32; off >= 1; off >>= 1) {
        s  += __shfl_xor(s,  off, 64);
        sq += __shfl_xor(sq, off, 64);
    }
    float mu  = s * (1.0f / CH);
    float var = sq * (1.0f / CH) - mu * mu;
    float rs  = rsqrtf(var + 1e-5f);
    float4 g0 = *(const float4*)&g[c0];
    float4 g1 = *(const float4*)&g[c0 + 4];
    float4 b0 = *(const float4*)&b[c0];
    float4 b1 = *(const float4*)&b[c0 + 4];
    __align__(16) bf16 t[8];
    t[0] = __float2bfloat16((v0.x - mu) * rs * g0.x + b0.x);
    t[1] = __float2bfloat16((v0.y - mu) * rs * g0.y + b0.y);
    t[2] = __float2bfloat16((v0.z - mu) * rs * g0.z + b0.z);
    t[3] = __float2bfloat16((v0.w - mu) * rs * g0.w + b0.w);
    t[4] = __float2bfloat16((v1.x - mu) * rs * g1.x + b1.x);
    t[5] = __float2bfloat16((v1.y - mu) * rs * g1.y + b1.y);
    t[6] = __float2bfloat16((v1.z - mu) * rs * g1.z + b1.z);
    t[7] = __float2bfloat16((v1.w - mu) * rs * g1.w + b1.w);
    *(uint4*)&out[(size_t)row * CH + c0] = *(const uint4*)t;
}

// ---------------- GEMM: C[M,N] = A[M,K] * B[N,K]^T, bf16 in, epilogues ----------------
// EPI 0: outB = bf16(acc)                       (qkv)
// EPI 1: outF = acc + bias[col] + resid[idx]    (proj / fc2, fp32 out)
// EPI 2: outB = bf16(gelu(acc + bias[col]))     (fc1)
template<int EPI>
__global__ __launch_bounds__(256)
void gemm_bt(const bf16* __restrict__ A, const bf16* __restrict__ Bw,
             int M, int N, int K,
             const float* __restrict__ bias,
             const float* resid, float* outF, bf16* __restrict__ outB) {
    __shared__ __align__(16) bf16 sA[2][128][32];
    __shared__ __align__(16) bf16 sB[2][128][32];
    const int tid  = threadIdx.x;
    const int wid  = tid >> 6;
    const int lane = tid & 63;
    const int bm   = blockIdx.y * 128;
    const int bn   = blockIdx.x * 128;
    const int wr   = (wid >> 1) * 64;   // wave row offset in tile
    const int wc   = (wid & 1) * 64;    // wave col offset in tile
    const int srow = lane >> 2;         // staging row within 16-row chunk
    const int scol = (lane & 3) * 8;    // staging k-element offset

    f32x4 acc[4][4] = {};
    const int nk = K >> 5;

    auto stage = [&](int buf, int kt) {
        int k0 = kt * 32 + scol;
#pragma unroll
        for (int cc = 0; cc < 2; ++cc) {
            int c = wid * 2 + cc;
            const bf16* ga = A  + (size_t)(bm + c * 16 + srow) * K + k0;
            __builtin_amdgcn_global_load_lds(
                (const __attribute__((address_space(1))) void*)ga,
                (__attribute__((address_space(3))) void*)&sA[buf][c * 16][0],
                16, 0, 0);
            const bf16* gb = Bw + (size_t)(bn + c * 16 + srow) * K + k0;
            __builtin_amdgcn_global_load_lds(
                (const __attribute__((address_space(1))) void*)gb,
                (__attribute__((address_space(3))) void*)&sB[buf][c * 16][0],
                16, 0, 0);
        }
    };

    auto compute = [&](int buf) {
        bf16x8 av[4], bv[4];
#pragma unroll
        for (int m = 0; m < 4; ++m)
            av[m] = *(const bf16x8*)&sA[buf][wr + m * 16 + (lane & 15)][(lane >> 4) * 8];
#pragma unroll
        for (int n = 0; n < 4; ++n)
            bv[n] = *(const bf16x8*)&sB[buf][wc + n * 16 + (lane & 15)][(lane >> 4) * 8];
#pragma unroll
        for (int m = 0; m < 4; ++m)
#pragma unroll
            for (int n = 0; n < 4; ++n)
                acc[m][n] = __builtin_amdgcn_mfma_f32_16x16x32_bf16(av[m], bv[n], acc[m][n], 0, 0, 0);
    };

    stage(0, 0);
    __syncthreads();
    int cur = 0;
    for (int kt = 0; kt < nk - 1; ++kt) {
        stage(cur ^ 1, kt + 1);
        compute(cur);
        __syncthreads();
        cur ^= 1;
    }
    compute(cur);

    // epilogue: D row = (lane>>4)*4 + r, col = lane&15 within each 16x16 frag
    const int erow0 = wr + (lane >> 4) * 4;
    const int ecol  = wc + (lane & 15);
#pragma unroll
    for (int m = 0; m < 4; ++m) {
#pragma unroll
        for (int n = 0; n < 4; ++n) {
            int col = bn + ecol + n * 16;
#pragma unroll
            for (int r = 0; r < 4; ++r) {
                int row = bm + erow0 + m * 16 + r;
                size_t idx = (size_t)row * N + col;
                float v = acc[m][n][r];
                if (EPI == 0) {
                    outB[idx] = __float2bfloat16(v);
                } else if (EPI == 1) {
                    outF[idx] = v + bias[col] + resid[idx];
                } else {
                    float t = v + bias[col];
                    float ge = 0.5f * t * (1.0f + erff(t * 0.70710678118654752f));
                    outB[idx] = __float2bfloat16(ge);
                }
            }
        }
    }
}

// ---------------- windowed attention: one block per window ----------------
// qkv row layout per token: [3][H][HD]; q at h*64, k at 512+h*64, v at 1024+h*64
__global__ __launch_bounds__(256)
void attn_kernel(const bf16* __restrict__ qkv, const float* __restrict__ rpb,
                 bf16* __restrict__ o) {
    __shared__ __align__(16) bf16 sT[4 * 1536];
    __shared__ float sS[NH][4][4];
    __shared__ float sP[NH][4][4];
    int b   = blockIdx.x;
    int tid = threadIdx.x;
    const bf16* src = qkv + (size_t)b * (4 * 1536);
#pragma unroll
    for (int it = 0; it < 3; ++it) {
        int e = (it * 256 + tid) * 8;
        *(uint4*)&sT[e] = *(const uint4*)&src[e];
    }
    __syncthreads();
    if (tid < 128) {
        int h = tid >> 4, i = (tid >> 2) & 3, j = tid & 3;
        const bf16* q = &sT[i * 1536 + h * 64];
        const bf16* k = &sT[j * 1536 + 512 + h * 64];
        float acc = 0.f;
#pragma unroll
        for (int d = 0; d < 64; ++d)
            acc += __bfloat162float(q[d]) * __bfloat162float(k[d]);
        int rel = (((i >> 1) - (j >> 1)) + 1) * 3 + (((i & 1) - (j & 1)) + 1);
        sS[h][i][j] = acc * 0.125f + rpb[rel * NH + h];
    }
    __syncthreads();
    if (tid < 32) {
        int h = tid >> 2, i = tid & 3;
        float s0 = sS[h][i][0], s1 = sS[h][i][1], s2 = sS[h][i][2], s3 = sS[h][i][3];
        float mx = fmaxf(fmaxf(s0, s1), fmaxf(s2, s3));
        float e0 = expf(s0 - mx), e1 = expf(s1 - mx), e2 = expf(s2 - mx), e3 = expf(s3 - mx);
        float inv = 1.f / (e0 + e1 + e2 + e3);
        sP[h][i][0] = e0 * inv; sP[h][i][1] = e1 * inv;
        sP[h][i][2] = e2 * inv; sP[h][i][3] = e3 * inv;
    }
    __syncthreads();
    {
        int h = tid >> 5, tl = tid & 31;
        int d = tl * 2;
        const bf16* v = &sT[1024 + h * 64 + d];
#pragma unroll
        for (int i = 0; i < 4; ++i) {
            float p0 = sP[h][i][0], p1 = sP[h][i][1], p2 = sP[h][i][2], p3 = sP[h][i][3];
            float o0 = p0 * __bfloat162float(v[0])        + p1 * __bfloat162float(v[1536])
                     + p2 * __bfloat162float(v[2 * 1536]) + p3 * __bfloat162float(v[3 * 1536]);
            float o1 = p0 * __bfloat162float(v[1])            + p1 * __bfloat162float(v[1536 + 1])
                     + p2 * __bfloat162float(v[2 * 1536 + 1]) + p3 * __bfloat162float(v[3 * 1536 + 1]);
            __hip_bfloat162 pr;
            pr.x = __float2bfloat16(o0);
            pr.y = __float2bfloat16(o1);
            *(__hip_bfloat162*)&o[(size_t)(b * 4 + i) * CH + h * 64 + d] = pr;
        }
    }
}

extern "C" void kernel_launch(void* const* d_in, const int* in_sizes, int n_in,
                              void* d_out, int out_size, void* d_ws, size_t ws_size,
                              hipStream_t stream) {
    const float* x      = (const float*)d_in[0];
    const float* ln_g   = (const float*)d_in[1];
    const float* ln_b   = (const float*)d_in[2];
    const float* qkv_w  = (const float*)d_in[3];
    const float* proj_w = (const float*)d_in[4];
    const float* proj_b = (const float*)d_in[5];
    const float* rpb    = (const float*)d_in[6];
    const float* fc1_w  = (const float*)d_in[7];
    const float* fc1_b  = (const float*)d_in[8];
    const float* fc2_w  = (const float*)d_in[9];
    const float* fc2_b  = (const float*)d_in[10];
    float* out = (float*)d_out;

    // workspace layout (16B aligned throughout)
    char* ws = (char*)d_ws;
    bf16* wQKV  = (bf16*)ws;  ws += (size_t)1536 * 512 * 2;   // 1.5 MB
    bf16* wPROJ = (bf16*)ws;  ws += (size_t)512  * 512 * 2;   // 0.5 MB
    bf16* wFC1  = (bf16*)ws;  ws += (size_t)2048 * 512 * 2;   // 2 MB
    bf16* wFC2  = (bf16*)ws;  ws += (size_t)512 * 2048 * 2;   // 2 MB
    bf16* hA    = (bf16*)ws;  ws += (size_t)NTOK * 512 * 2;   // 64 MB: h_ln -> o -> h2
    bf16* big   = (bf16*)ws;                                  // 256 MB: qkv -> fc1 out
    const size_t needed = 6291456ull + 67108864ull + 268435456ull;
    if (ws_size < needed) return;  // fail loudly (output stays poisoned)

    // weight conversion
    f2b_kernel<<<768,  256, 0, stream>>>(qkv_w,  wQKV, 1536 * 512);
    f2b_kernel<<<256,  256, 0, stream>>>(proj_w, wPROJ, 512 * 512);
    f2b_kernel<<<1024, 256, 0, stream>>>(fc1_w,  wFC1, 2048 * 512);
    f2b_kernel<<<1024, 256, 0, stream>>>(fc2_w,  wFC2, 512 * 2048);

    // LN1: x -> hA (bf16)
    ln_kernel<<<NTOK / 4, 256, 0, stream>>>(x, ln_g, ln_b, hA);
    // qkv = hA @ qkv_w^T  -> big
    gemm_bt<0><<<dim3(1536 / 128, NTOK / 128), 256, 0, stream>>>(
        hA, wQKV, NTOK, 1536, 512, nullptr, nullptr, nullptr, big);
    // attention: big -> hA (o)
    attn_kernel<<<BQ, 256, 0, stream>>>(big, rpb, hA);
    // x1 = x + o @ proj_w^T + proj_b -> out (fp32)
    gemm_bt<1><<<dim3(512 / 128, NTOK / 128), 256, 0, stream>>>(
        hA, wPROJ, NTOK, 512, 512, proj_b, x, out, nullptr);
    // LN2: out -> hA (h2)
    ln_kernel<<<NTOK / 4, 256, 0, stream>>>(out, ln_g, ln_b, hA);
    // g = gelu(h2 @ fc1_w^T + fc1_b) -> big (bf16)
    gemm_bt<2><<<dim3(2048 / 128, NTOK / 128), 256, 0, stream>>>(
        hA, wFC1, NTOK, 2048, 512, fc1_b, nullptr, nullptr, big);
    // out = x1 + g @ fc2_w^T + fc2_b (in-place residual read)
    gemm_bt<1><<<dim3(512 / 128, NTOK / 128), 256, 0, stream>>>(
        big, wFC2, NTOK, 512, 2048, fc2_b, out, out, nullptr);
}